// Round 7
// baseline (23.010 us; speedup 1.0000x reference)
//
#include <hip/hip_runtime.h>

// Tree positional embedding, closed form:
//   out[i][8*j + child_idx(ancestor_j(i))] = 1.0 for j < min(depth[i], K), else 0
// BRANCH=8, K_DEPTH=16 (h = 128 floats/row).
//
// R3 structure scaled: 256 rows/block (128 KB output/block), 256 threads.
//   Phase 1: ALL 256 threads walk one row each (R3 used only 128), pack hot
//            columns (3 bits/level) + clamped depth into u64 codes in LDS.
//   Phase 2: per-thread constants: c = tid&31 (float4 chunk), j = c>>1 (slot),
//            shift = 3j, window r0 = 4c-8j in {0,4}. 32 unrolled iterations:
//            LDS code read (broadcast), extract, 4 cmp/cndmask, one coalesced
//            dwordx4 store. Halves block count (782) and barriers per byte vs
//            R3; doubles the streaming run per thread.

#define PE_K 16
#define ROWS_PER_BLOCK 256

typedef float vf4 __attribute__((ext_vector_type(4)));

__global__ __launch_bounds__(256) void PositionalEmbedding_kernel(
    const int* __restrict__ parent,
    const int* __restrict__ child_idx,
    const int* __restrict__ depth,
    float* __restrict__ out,
    int N) {
  __shared__ unsigned long long codes[ROWS_PER_BLOCK];

  const int tid  = threadIdx.x;
  const int row0 = blockIdx.x * ROWS_PER_BLOCK;

  // ---- Phase 1: every thread builds one row's packed ancestor code ----
  {
    int row = row0 + tid;
    unsigned long long code = 0;
    if (row < N) {
      int d  = depth[row];
      int dd = d < PE_K ? d : PE_K;
      int cur = row;
      for (int j = 0; j < dd; ++j) {
        int ci = child_idx[cur] & 7;
        code |= (unsigned long long)ci << (3 * j);
        cur = parent[cur];
      }
      code |= (unsigned long long)dd << 48;
    }
    codes[tid] = code;
  }
  __syncthreads();

  // ---- Phase 2: stream 256 rows x 32 float4, all constants hoisted ----
  const int c  = tid & 31;        // float4 chunk within row (constant)
  const int g  = tid >> 5;        // row-group 0..7 (constant)
  const int j  = c >> 1;          // 8-wide level slot (constant)
  const int sh = 3 * j;           // code shift (constant)
  const int r0 = 4 * c - 8 * j;   // compare window base: 0 or 4 (constant)

  vf4* p = reinterpret_cast<vf4*>(out) + ((long long)(row0 + g) * 32 + c);
  const int last_full_rl = N - row0;   // rows with rl < this are valid

  #pragma unroll
  for (int it = 0; it < ROWS_PER_BLOCK / 8; ++it) {
    int rl = it * 8 + g;
    unsigned long long code = codes[rl];
    int dd = (int)(code >> 48);
    int ci = (int)((code >> sh) & 7);
    ci = (j < dd) ? ci : 8;            // 8 = matches nothing -> zeros

    vf4 v;
    v.x = (ci == r0 + 0) ? 1.f : 0.f;
    v.y = (ci == r0 + 1) ? 1.f : 0.f;
    v.z = (ci == r0 + 2) ? 1.f : 0.f;
    v.w = (ci == r0 + 3) ? 1.f : 0.f;

    if (rl < last_full_rl) *p = v;     // only the last block is ever partial
    p += 8 * 32;                       // advance 8 rows
  }
}

extern "C" void kernel_launch(void* const* d_in, const int* in_sizes, int n_in,
                              void* d_out, int out_size, void* d_ws, size_t ws_size,
                              hipStream_t stream) {
  const int* parent    = (const int*)d_in[0];
  const int* child_idx = (const int*)d_in[1];
  const int* depth     = (const int*)d_in[2];
  // d_in[3] = p_emb (unused), d_in[4] = n (=8), d_in[5] = k (=16)
  float* out = (float*)d_out;
  int N = in_sizes[0];

  int grid = (N + ROWS_PER_BLOCK - 1) / ROWS_PER_BLOCK;   // 782 @ N=200k
  PositionalEmbedding_kernel<<<grid, 256, 0, stream>>>(parent, child_idx, depth, out, N);
}